// Round 4
// baseline (371.961 us; speedup 1.0000x reference)
//
#include <hip/hip_runtime.h>
#include <math.h>

#define NN 100000
#define NE 1600000
#define F_IN 128
#define C 128           // N_HEADS * F_OUT
#define NEG_SLOPE 0.2f
#define PROJ_NB ((NN + 63) / 64)       // 1563

// counting-sort geometry
#define NBLK1 256                       // pass1/pass2 blocks
#define EPB ((NE + NBLK1 - 1) / NBLK1)  // 6250 edges per block
#define BSHIFT 9
#define NBUCK ((NN + 511) / 512)        // 196 (buckets indexed by dst>>9)

// agg geometry
#define AGG_NB 64                       // dst nodes per block
#define AGG_GRID ((NN + AGG_NB - 1) / AGG_NB)   // 1563
#define ASTRIDE 132                     // acc row stride (floats), kills bank alias

typedef __attribute__((ext_vector_type(8))) short short8;    // 8 x bf16
typedef __attribute__((ext_vector_type(4))) float f32x4;
typedef __attribute__((ext_vector_type(4))) float floatx4;
typedef __attribute__((ext_vector_type(4))) unsigned short ushortx4;

static __device__ __forceinline__ unsigned short f2bf(float f) {
    unsigned int u = __float_as_uint(f);
    unsigned int r = (u + 0x7fff + ((u >> 16) & 1)) >> 16;  // RNE
    return (unsigned short)r;
}
static __device__ __forceinline__ float bf2f(unsigned short h) {
    return __uint_as_float((unsigned int)h << 16);
}
static __device__ __forceinline__ float lrelu(float x) {
    return (x > 0.f) ? x : NEG_SLOPE * x;
}

// ---------------------------------------------------------------------------
// Btf: fragment-major B for mfma_f32_16x16x32_bf16.
// ---------------------------------------------------------------------------
__global__ __launch_bounds__(256)
void wconv_kernel(const float* __restrict__ W,
                  const float* __restrict__ Wr,
                  unsigned short* __restrict__ Btf)
{
    int g = blockIdx.x * 256 + threadIdx.x;   // 0..4095
    int nt = g >> 8;
    int kc = (g >> 6) & 3;
    int l  = g & 63;
    int n  = nt * 16 + (l & 15);
    int kb = kc * 32 + (l >> 4) * 8;
    unsigned short v[8];
    #pragma unroll
    for (int j = 0; j < 8; ++j) {
        int k = kb + j;
        float f = (n < 128) ? W[(size_t)k * 128 + n] : Wr[(size_t)k * 128 + (n - 128)];
        v[j] = f2bf(f);
    }
    *(short8*)&Btf[(size_t)g * 8] = *(short8*)v;
}

// ---------------------------------------------------------------------------
// Projection GEMM (no atomics). A fragments straight from feat; B fragments
// straight from L2-resident Btf.
// ---------------------------------------------------------------------------
__global__ __launch_bounds__(256, 4)
void proj_kernel(const float* __restrict__ feat,
                 const unsigned short* __restrict__ Btf,
                 const float* __restrict__ att_src,
                 const float* __restrict__ att_dst,
                 unsigned short* __restrict__ xb,
                 unsigned short* __restrict__ resb,
                 float* __restrict__ a_s,
                 float* __restrict__ a_d)
{
    __shared__ __align__(16) float T2all[4][16 * 68];  // 17408B, wave-private
    __shared__ float s_as[64][4];
    __shared__ float s_ad[64][4];
    const int tid = threadIdx.x;

    const int base = blockIdx.x * 64;
    const int l = tid & 63;
    const int w = tid >> 6;
    const int quad = l >> 4;
    const int lo16 = l & 15;
    const int arow = w * 16 + lo16;
    const int nclamp = min(base + arow, NN - 1);   // safe row for last block

    short8 af[4];
    #pragma unroll
    for (int kc = 0; kc < 4; ++kc) {
        const float* fp = &feat[(size_t)nclamp * F_IN + kc * 32 + quad * 8];
        floatx4 f0 = __builtin_nontemporal_load((const floatx4*)fp);
        floatx4 f1 = __builtin_nontemporal_load((const floatx4*)(fp + 4));
        unsigned short v[8];
        v[0] = f2bf(f0.x); v[1] = f2bf(f0.y); v[2] = f2bf(f0.z); v[3] = f2bf(f0.w);
        v[4] = f2bf(f1.x); v[5] = f2bf(f1.y); v[6] = f2bf(f1.z); v[7] = f2bf(f1.w);
        af[kc] = *(short8*)v;
    }

    f32x4 acc[16];
    #pragma unroll
    for (int nt = 0; nt < 16; ++nt) acc[nt] = (f32x4){0.f, 0.f, 0.f, 0.f};

    #pragma unroll
    for (int nt = 0; nt < 16; ++nt) {
        const unsigned short* bp = &Btf[(size_t)(nt * 4) * 512 + l * 8];
        short8 b0 = *(const short8*)&bp[0];
        short8 b1 = *(const short8*)&bp[512];
        short8 b2 = *(const short8*)&bp[1024];
        short8 b3 = *(const short8*)&bp[1536];
        acc[nt] = __builtin_amdgcn_mfma_f32_16x16x32_bf16(af[0], b0, acc[nt], 0, 0, 0);
        acc[nt] = __builtin_amdgcn_mfma_f32_16x16x32_bf16(af[1], b1, acc[nt], 0, 0, 0);
        acc[nt] = __builtin_amdgcn_mfma_f32_16x16x32_bf16(af[2], b2, acc[nt], 0, 0, 0);
        acc[nt] = __builtin_amdgcn_mfma_f32_16x16x32_bf16(af[3], b3, acc[nt], 0, 0, 0);
    }

    float* T2 = T2all[w];           // wave-private [16][68]
    const int g  = l >> 4;
    const int cf = (l & 15) * 4;

    #pragma unroll
    for (int p = 0; p < 2; ++p) {
        #pragma unroll
        for (int ntl = 0; ntl < 4; ++ntl) {
            int nt = p * 4 + ntl;
            #pragma unroll
            for (int r = 0; r < 4; ++r)
                T2[(quad * 4 + r) * 68 + ntl * 16 + lo16] = acc[nt][r];
        }
        floatx4 ws4 = *(const floatx4*)&att_src[p * 64 + cf];
        floatx4 wd4 = *(const floatx4*)&att_dst[p * 64 + cf];
        float ps[4], pd[4];
        #pragma unroll
        for (int it = 0; it < 4; ++it) {
            int row = it * 4 + g;
            floatx4 v = *(floatx4*)&T2[row * 68 + cf];
            int node = base + w * 16 + row;
            ushortx4 hh;
            hh.x = f2bf(v.x); hh.y = f2bf(v.y); hh.z = f2bf(v.z); hh.w = f2bf(v.w);
            if (node < NN)
                __builtin_nontemporal_store(hh,
                    (ushortx4*)&xb[(size_t)node * C + p * 64 + cf]);
            ps[it] = v.x * ws4.x + v.y * ws4.y + v.z * ws4.z + v.w * ws4.w;
            pd[it] = v.x * wd4.x + v.y * wd4.y + v.z * wd4.z + v.w * wd4.w;
        }
        #pragma unroll
        for (int it = 0; it < 4; ++it) {
            #pragma unroll
            for (int d = 1; d < 8; d <<= 1) {
                ps[it] += __shfl_xor(ps[it], d, 64);
                pd[it] += __shfl_xor(pd[it], d, 64);
            }
        }
        if ((l & 7) == 0) {
            int hh = p * 2 + ((l & 15) >> 3);
            #pragma unroll
            for (int it = 0; it < 4; ++it) {
                int lr = w * 16 + it * 4 + g;
                s_as[lr][hh] = ps[it];
                s_ad[lr][hh] = pd[it];
            }
        }
    }

    #pragma unroll
    for (int p = 0; p < 2; ++p) {
        #pragma unroll
        for (int ntl = 0; ntl < 4; ++ntl) {
            int nt = 8 + p * 4 + ntl;
            #pragma unroll
            for (int r = 0; r < 4; ++r)
                T2[(quad * 4 + r) * 68 + ntl * 16 + lo16] = acc[nt][r];
        }
        #pragma unroll
        for (int it = 0; it < 4; ++it) {
            int row = it * 4 + g;
            floatx4 v = *(floatx4*)&T2[row * 68 + cf];
            int node = base + w * 16 + row;
            ushortx4 hh;
            hh.x = f2bf(v.x); hh.y = f2bf(v.y); hh.z = f2bf(v.z); hh.w = f2bf(v.w);
            if (node < NN)
                __builtin_nontemporal_store(hh,
                    (ushortx4*)&resb[(size_t)node * C + p * 64 + cf]);
        }
    }

    __syncthreads();
    int idx = blockIdx.x * 256 + tid;
    if (idx < NN * 4) {
        a_s[idx] = ((float*)s_as)[tid];
        a_d[idx] = ((float*)s_ad)[tid];
    }
}

// ---------------------------------------------------------------------------
// CSR build via two-level counting sort. NO global atomics anywhere.
// ---------------------------------------------------------------------------
__global__ __launch_bounds__(256)
void sort1_kernel(const int* __restrict__ dst, int* __restrict__ counts)
{
    __shared__ int h[256];
    const int tid = threadIdx.x;
    h[tid] = 0;
    __syncthreads();
    const int e0 = blockIdx.x * EPB;
    const int e1 = min(NE, e0 + EPB);
    for (int e = e0 + tid; e < e1; e += 256)
        atomicAdd(&h[dst[e] >> BSHIFT], 1);
    __syncthreads();
    counts[blockIdx.x * 256 + tid] = h[tid];
}

__global__ __launch_bounds__(256)
void sortscan_kernel(int* __restrict__ counts, int* __restrict__ bucket_base)
{
    __shared__ int wsum[4];
    const int t = threadIdx.x, lane = t & 63, wid = t >> 6;
    int run = 0;
    #pragma unroll 8
    for (int b = 0; b < NBLK1; ++b) {
        int v = counts[b * 256 + t];
        counts[b * 256 + t] = run;
        run += v;
    }
    int v0 = run, v = run;
    #pragma unroll
    for (int off = 1; off < 64; off <<= 1) {
        int u = __shfl_up(v, off, 64);
        if (lane >= off) v += u;
    }
    if (lane == 63) wsum[wid] = v;
    __syncthreads();
    if (t == 0) {
        int r = 0;
        #pragma unroll
        for (int s = 0; s < 4; ++s) { int tmp = wsum[s]; wsum[s] = r; r += tmp; }
    }
    __syncthreads();
    int excl = wsum[wid] + (v - v0);
    bucket_base[t] = excl;
    if (t == 255) bucket_base[256] = excl + v0;   // == NE
}

// pass2: scatter edges into bucket-major packed array via LDS cursors.
// bpack = (dst&511)<<20 | src   (src < 2^17)
__global__ __launch_bounds__(256)
void sort2_kernel(const int* __restrict__ src, const int* __restrict__ dst,
                  const int* __restrict__ counts,
                  const int* __restrict__ bucket_base,
                  int* __restrict__ bpack)
{
    __shared__ int cur[256];
    const int tid = threadIdx.x;
    cur[tid] = bucket_base[tid] + counts[blockIdx.x * 256 + tid];
    __syncthreads();
    const int e0 = blockIdx.x * EPB;
    const int e1 = min(NE, e0 + EPB);
    for (int e = e0 + tid; e < e1; e += 256) {
        int d = dst[e];
        int s = src[e];
        int pos = atomicAdd(&cur[d >> BSHIFT], 1);
        bpack[pos] = ((d & 511) << 20) | s;
    }
}

// pass3: per-bucket (512 nodes) CSR finalize + softmax DENOMINATORS.
// csr_pack keeps the full (dstLocal<<20)|src word for the edge-parallel agg.
__global__ __launch_bounds__(512)
void sort3_kernel(const int* __restrict__ bpack,
                  const int* __restrict__ bucket_base,
                  const float* __restrict__ a_s,
                  const float* __restrict__ a_d,
                  int* __restrict__ row_ptr,
                  int* __restrict__ csr_pack,
                  float* __restrict__ inv_den)
{
    __shared__ int cnt[512];
    __shared__ int curs[512];
    __shared__ int wsum[8];
    __shared__ float sden[512 * 4];
    const int t = threadIdx.x, lane = t & 63, wid = t >> 6;
    const int b = blockIdx.x;
    const int ebeg = bucket_base[b];
    const int eend = bucket_base[b + 1];
    cnt[t] = 0;
    #pragma unroll
    for (int j = 0; j < 4; ++j) sden[t + j * 512] = 0.f;
    __syncthreads();
    for (int e = ebeg + t; e < eend; e += 512) {
        int p = bpack[e];
        int dl = p >> 20;
        int s  = p & 0xFFFFF;
        atomicAdd(&cnt[dl], 1);
        float4 as4 = *(const float4*)&a_s[(size_t)s * 4];
        float4 ad4 = *(const float4*)&a_d[(size_t)((b << BSHIFT) + dl) * 4];
        atomicAdd(&sden[dl * 4 + 0], __expf(lrelu(as4.x + ad4.x)));
        atomicAdd(&sden[dl * 4 + 1], __expf(lrelu(as4.y + ad4.y)));
        atomicAdd(&sden[dl * 4 + 2], __expf(lrelu(as4.z + ad4.z)));
        atomicAdd(&sden[dl * 4 + 3], __expf(lrelu(as4.w + ad4.w)));
    }
    __syncthreads();
    int v0 = cnt[t], v = v0;
    #pragma unroll
    for (int off = 1; off < 64; off <<= 1) {
        int u = __shfl_up(v, off, 64);
        if (lane >= off) v += u;
    }
    if (lane == 63) wsum[wid] = v;
    __syncthreads();
    if (t == 0) {
        int r = 0;
        #pragma unroll
        for (int s = 0; s < 8; ++s) { int tmp = wsum[s]; wsum[s] = r; r += tmp; }
    }
    __syncthreads();
    int excl = wsum[wid] + (v - v0);
    curs[t] = excl;
    int n = (b << BSHIFT) + t;
    if (n < NN) {
        row_ptr[n] = ebeg + excl;
        float d0 = sden[t * 4 + 0], d1 = sden[t * 4 + 1];
        float d2 = sden[t * 4 + 2], d3 = sden[t * 4 + 3];
        inv_den[n * 4 + 0] = (d0 > 0.f) ? 1.f / d0 : 0.f;
        inv_den[n * 4 + 1] = (d1 > 0.f) ? 1.f / d1 : 0.f;
        inv_den[n * 4 + 2] = (d2 > 0.f) ? 1.f / d2 : 0.f;
        inv_den[n * 4 + 3] = (d3 > 0.f) ? 1.f / d3 : 0.f;
    }
    if (b == NBUCK - 1 && t == 0) row_ptr[NN] = NE;
    __syncthreads();
    for (int e = ebeg + t; e < eend; e += 512) {
        int p = bpack[e];
        int pos = atomicAdd(&curs[p >> 20], 1);
        csr_pack[ebeg + pos] = p;           // keep full pack
    }
}

// ---------------------------------------------------------------------------
// EDGE-PARALLEL aggregation. Block owns 64 consecutive dst nodes; its edge
// range [row_ptr[n0], row_ptr[n0+64]) is split evenly across 16 quads
// (perfect balance, zero per-node serialization). Per edge: quad reads packed
// (dstLocal|src), recomputes alpha (a_s table is L2-resident), FMAs the xb
// row into regs; flush to LDS acc via ds_add_f32 only on dst-run change.
// 3-deep software pipeline => 3 independent rows in flight per quad.
// ---------------------------------------------------------------------------
__global__ __launch_bounds__(256)
void agg_kernel(const unsigned short* __restrict__ xb,
                const unsigned short* __restrict__ resb,
                const float* __restrict__ a_s,
                const float* __restrict__ a_d,
                const float* __restrict__ inv_den,
                const int* __restrict__ row_ptr,
                const int* __restrict__ csr_pack,
                float* __restrict__ out)
{
    __shared__ float accL[AGG_NB * ASTRIDE];   // 33792 B
    __shared__ float lds_ad[AGG_NB * 4];
    __shared__ float lds_inv[AGG_NB * 4];
    const int tid = threadIdx.x;
    const int n0 = blockIdx.x * AGG_NB;

    {
        int nidx = n0 * 4 + tid;
        float adv = 0.f, ivv = 0.f;
        if (nidx < NN * 4) { adv = a_d[nidx]; ivv = inv_den[nidx]; }
        lds_ad[tid] = adv;
        lds_inv[tid] = ivv;
    }
    #pragma unroll
    for (int i = 0; i < (AGG_NB * ASTRIDE) / 256; ++i)
        accL[tid + i * 256] = 0.f;

    const int rp0 = row_ptr[n0];
    const int rpN = row_ptr[min(n0 + AGG_NB, NN)];
    __syncthreads();

    const int ecnt = rpN - rp0;
    const int gq  = tid >> 4;      // quad 0..15
    const int t16 = tid & 15;
    const int h   = t16 >> 2;
    const int chunk = (ecnt + 15) >> 4;
    const int ebeg = rp0 + gq * chunk;
    const int eend = min(rpN, ebeg + chunk);

    if (ebeg < eend) {
        // 3-deep pipeline state: edge i has (p, as, uv) resident/in-flight
        int p0 = csr_pack[ebeg];
        int s0 = p0 & 0xFFFFF;
        float as0 = a_s[(size_t)s0 * 4 + h];
        short8 uv0 = *(const short8*)&xb[(size_t)s0 * C + t16 * 8];
        int p1 = p0; float as1 = as0; short8 uv1 = uv0;
        if (ebeg + 1 < eend) {
            p1 = csr_pack[ebeg + 1];
            int s1 = p1 & 0xFFFFF;
            as1 = a_s[(size_t)s1 * 4 + h];
            uv1 = *(const short8*)&xb[(size_t)s1 * C + t16 * 8];
        }

        int cur = (p0 >> 20) & 63;
        float ad_h  = lds_ad[cur * 4 + h];
        float inv_h = lds_inv[cur * 4 + h];
        float a0 = 0.f, a1 = 0.f, a2 = 0.f, a3 = 0.f;
        float a4 = 0.f, a5 = 0.f, a6 = 0.f, a7 = 0.f;

        for (int e = ebeg; e < eend; ++e) {
            // issue edge e+2
            int p2 = p0; float as2 = as0; short8 uv2 = uv0;
            if (e + 2 < eend) {
                p2 = csr_pack[e + 2];
                int s2 = p2 & 0xFFFFF;
                as2 = a_s[(size_t)s2 * 4 + h];
                uv2 = *(const short8*)&xb[(size_t)s2 * C + t16 * 8];
            }
            // process edge e
            int nl = (p0 >> 20) & 63;
            if (nl != cur) {
                float* fr = &accL[cur * ASTRIDE + t16 * 8];
                atomicAdd(&fr[0], a0); atomicAdd(&fr[1], a1);
                atomicAdd(&fr[2], a2); atomicAdd(&fr[3], a3);
                atomicAdd(&fr[4], a4); atomicAdd(&fr[5], a5);
                atomicAdd(&fr[6], a6); atomicAdd(&fr[7], a7);
                a0 = a1 = a2 = a3 = a4 = a5 = a6 = a7 = 0.f;
                cur = nl;
                ad_h  = lds_ad[nl * 4 + h];
                inv_h = lds_inv[nl * 4 + h];
            }
            float al = __expf(lrelu(as0 + ad_h)) * inv_h;
            a0 = fmaf(al, bf2f((unsigned short)uv0[0]), a0);
            a1 = fmaf(al, bf2f((unsigned short)uv0[1]), a1);
            a2 = fmaf(al, bf2f((unsigned short)uv0[2]), a2);
            a3 = fmaf(al, bf2f((unsigned short)uv0[3]), a3);
            a4 = fmaf(al, bf2f((unsigned short)uv0[4]), a4);
            a5 = fmaf(al, bf2f((unsigned short)uv0[5]), a5);
            a6 = fmaf(al, bf2f((unsigned short)uv0[6]), a6);
            a7 = fmaf(al, bf2f((unsigned short)uv0[7]), a7);
            // rotate
            p0 = p1; as0 = as1; uv0 = uv1;
            p1 = p2; as1 = as2; uv1 = uv2;
        }
        {   // final flush
            float* fr = &accL[cur * ASTRIDE + t16 * 8];
            atomicAdd(&fr[0], a0); atomicAdd(&fr[1], a1);
            atomicAdd(&fr[2], a2); atomicAdd(&fr[3], a3);
            atomicAdd(&fr[4], a4); atomicAdd(&fr[5], a5);
            atomicAdd(&fr[6], a6); atomicAdd(&fr[7], a7);
        }
    }
    __syncthreads();

    // output: thread -> (row, 32-col segment); coalesced resb read + out write
    const int r  = tid >> 2;
    const int c0 = (tid & 3) * 32;
    const int n  = n0 + r;
    if (n < NN) {
        const float* ap = &accL[r * ASTRIDE + c0];
        #pragma unroll
        for (int j = 0; j < 32; j += 8) {
            short8 rv = *(const short8*)&resb[(size_t)n * C + c0 + j];
            floatx4 o0, o1;
            o0.x = bf2f((unsigned short)rv[0]) + ap[j + 0];
            o0.y = bf2f((unsigned short)rv[1]) + ap[j + 1];
            o0.z = bf2f((unsigned short)rv[2]) + ap[j + 2];
            o0.w = bf2f((unsigned short)rv[3]) + ap[j + 3];
            o1.x = bf2f((unsigned short)rv[4]) + ap[j + 4];
            o1.y = bf2f((unsigned short)rv[5]) + ap[j + 5];
            o1.z = bf2f((unsigned short)rv[6]) + ap[j + 6];
            o1.w = bf2f((unsigned short)rv[7]) + ap[j + 7];
            __builtin_nontemporal_store(o0, (floatx4*)&out[(size_t)n * C + c0 + j]);
            __builtin_nontemporal_store(o1, (floatx4*)&out[(size_t)n * C + c0 + j + 4]);
        }
    }
}

// ---------------------------------------------------------------------------
extern "C" void kernel_launch(void* const* d_in, const int* in_sizes, int n_in,
                              void* d_out, int out_size, void* d_ws, size_t ws_size,
                              hipStream_t stream)
{
    const float* feat    = (const float*)d_in[0];
    const float* W       = (const float*)d_in[1];
    const float* att_src = (const float*)d_in[2];
    const float* att_dst = (const float*)d_in[3];
    const float* W_res   = (const float*)d_in[4];
    const int*   src     = (const int*)d_in[5];
    const int*   dst     = (const int*)d_in[6];
    float* out = (float*)d_out;

    char* p = (char*)d_ws;
    unsigned short* xb   = (unsigned short*)p; p += (size_t)NN * C * sizeof(unsigned short);
    unsigned short* resb = (unsigned short*)p; p += (size_t)NN * C * sizeof(unsigned short);
    unsigned short* Btf  = (unsigned short*)p; p += (size_t)256 * 128 * sizeof(unsigned short);
    float* a_s = (float*)p;            p += (size_t)NN * 4 * sizeof(float);
    float* a_d = (float*)p;            p += (size_t)NN * 4 * sizeof(float);
    float* inv_den = (float*)p;        p += (size_t)NN * 4 * sizeof(float);
    int* row_ptr = (int*)p;            p += (size_t)(NN + 1) * sizeof(int);
    int* counts  = (int*)p;            p += (size_t)NBLK1 * 256 * sizeof(int);
    int* bucket_base = (int*)p;        p += (size_t)257 * sizeof(int);
    int* bpack   = (int*)p;            p += (size_t)NE * sizeof(int);
    int* csr_pack = (int*)p;           p += (size_t)NE * sizeof(int);

    wconv_kernel<<<16, 256, 0, stream>>>(W, W_res, Btf);
    proj_kernel<<<PROJ_NB, 256, 0, stream>>>(
        feat, Btf, att_src, att_dst, xb, resb, a_s, a_d);
    sort1_kernel<<<NBLK1, 256, 0, stream>>>(dst, counts);
    sortscan_kernel<<<1, 256, 0, stream>>>(counts, bucket_base);
    sort2_kernel<<<NBLK1, 256, 0, stream>>>(src, dst, counts, bucket_base, bpack);
    sort3_kernel<<<NBUCK, 512, 0, stream>>>(bpack, bucket_base, a_s, a_d,
                                            row_ptr, csr_pack, inv_den);
    agg_kernel<<<AGG_GRID, 256, 0, stream>>>(xb, resb, a_s, a_d, inv_den,
                                             row_ptr, csr_pack, out);
}

// Round 5
// 262.289 us; speedup vs baseline: 1.4181x; 1.4181x over previous
//
#include <hip/hip_runtime.h>
#include <math.h>

#define NN 100000
#define NE 1600000
#define F_IN 128
#define C 128           // N_HEADS * F_OUT
#define NEG_SLOPE 0.2f
#define PROJ_NB ((NN + 63) / 64)       // 1563

// counting-sort geometry
#define NBLK1 256                       // pass1/pass2 blocks
#define EPB ((NE + NBLK1 - 1) / NBLK1)  // 6250 edges per block
#define BSHIFT 9
#define NBUCK ((NN + 511) / 512)        // 196 (buckets indexed by dst>>9)

typedef __attribute__((ext_vector_type(8))) short short8;    // 8 x bf16
typedef __attribute__((ext_vector_type(4))) float f32x4;
typedef __attribute__((ext_vector_type(4))) float floatx4;
typedef __attribute__((ext_vector_type(4))) unsigned short ushortx4;

static __device__ __forceinline__ unsigned short f2bf(float f) {
    unsigned int u = __float_as_uint(f);
    unsigned int r = (u + 0x7fff + ((u >> 16) & 1)) >> 16;  // RNE
    return (unsigned short)r;
}
static __device__ __forceinline__ float bf2f(unsigned short h) {
    return __uint_as_float((unsigned int)h << 16);
}
static __device__ __forceinline__ float lrelu(float x) {
    return (x > 0.f) ? x : NEG_SLOPE * x;
}

// ---------------------------------------------------------------------------
// Btf: fragment-major B for mfma_f32_16x16x32_bf16.
// ---------------------------------------------------------------------------
__global__ __launch_bounds__(256)
void wconv_kernel(const float* __restrict__ W,
                  const float* __restrict__ Wr,
                  unsigned short* __restrict__ Btf)
{
    int g = blockIdx.x * 256 + threadIdx.x;   // 0..4095
    int nt = g >> 8;
    int kc = (g >> 6) & 3;
    int l  = g & 63;
    int n  = nt * 16 + (l & 15);
    int kb = kc * 32 + (l >> 4) * 8;
    unsigned short v[8];
    #pragma unroll
    for (int j = 0; j < 8; ++j) {
        int k = kb + j;
        float f = (n < 128) ? W[(size_t)k * 128 + n] : Wr[(size_t)k * 128 + (n - 128)];
        v[j] = f2bf(f);
    }
    *(short8*)&Btf[(size_t)g * 8] = *(short8*)v;
}

// ---------------------------------------------------------------------------
// Projection GEMM (no atomics). A fragments straight from feat; B fragments
// straight from L2-resident Btf.
// ---------------------------------------------------------------------------
__global__ __launch_bounds__(256, 4)
void proj_kernel(const float* __restrict__ feat,
                 const unsigned short* __restrict__ Btf,
                 const float* __restrict__ att_src,
                 const float* __restrict__ att_dst,
                 unsigned short* __restrict__ xb,
                 unsigned short* __restrict__ resb,
                 float* __restrict__ a_s,
                 float* __restrict__ a_d)
{
    __shared__ __align__(16) float T2all[4][16 * 68];  // 17408B, wave-private
    __shared__ float s_as[64][4];
    __shared__ float s_ad[64][4];
    const int tid = threadIdx.x;

    const int base = blockIdx.x * 64;
    const int l = tid & 63;
    const int w = tid >> 6;
    const int quad = l >> 4;
    const int lo16 = l & 15;
    const int arow = w * 16 + lo16;
    const int nclamp = min(base + arow, NN - 1);   // safe row for last block

    short8 af[4];
    #pragma unroll
    for (int kc = 0; kc < 4; ++kc) {
        const float* fp = &feat[(size_t)nclamp * F_IN + kc * 32 + quad * 8];
        floatx4 f0 = __builtin_nontemporal_load((const floatx4*)fp);
        floatx4 f1 = __builtin_nontemporal_load((const floatx4*)(fp + 4));
        unsigned short v[8];
        v[0] = f2bf(f0.x); v[1] = f2bf(f0.y); v[2] = f2bf(f0.z); v[3] = f2bf(f0.w);
        v[4] = f2bf(f1.x); v[5] = f2bf(f1.y); v[6] = f2bf(f1.z); v[7] = f2bf(f1.w);
        af[kc] = *(short8*)v;
    }

    f32x4 acc[16];
    #pragma unroll
    for (int nt = 0; nt < 16; ++nt) acc[nt] = (f32x4){0.f, 0.f, 0.f, 0.f};

    #pragma unroll
    for (int nt = 0; nt < 16; ++nt) {
        const unsigned short* bp = &Btf[(size_t)(nt * 4) * 512 + l * 8];
        short8 b0 = *(const short8*)&bp[0];
        short8 b1 = *(const short8*)&bp[512];
        short8 b2 = *(const short8*)&bp[1024];
        short8 b3 = *(const short8*)&bp[1536];
        acc[nt] = __builtin_amdgcn_mfma_f32_16x16x32_bf16(af[0], b0, acc[nt], 0, 0, 0);
        acc[nt] = __builtin_amdgcn_mfma_f32_16x16x32_bf16(af[1], b1, acc[nt], 0, 0, 0);
        acc[nt] = __builtin_amdgcn_mfma_f32_16x16x32_bf16(af[2], b2, acc[nt], 0, 0, 0);
        acc[nt] = __builtin_amdgcn_mfma_f32_16x16x32_bf16(af[3], b3, acc[nt], 0, 0, 0);
    }

    float* T2 = T2all[w];           // wave-private [16][68]
    const int g  = l >> 4;
    const int cf = (l & 15) * 4;

    #pragma unroll
    for (int p = 0; p < 2; ++p) {
        #pragma unroll
        for (int ntl = 0; ntl < 4; ++ntl) {
            int nt = p * 4 + ntl;
            #pragma unroll
            for (int r = 0; r < 4; ++r)
                T2[(quad * 4 + r) * 68 + ntl * 16 + lo16] = acc[nt][r];
        }
        floatx4 ws4 = *(const floatx4*)&att_src[p * 64 + cf];
        floatx4 wd4 = *(const floatx4*)&att_dst[p * 64 + cf];
        float ps[4], pd[4];
        #pragma unroll
        for (int it = 0; it < 4; ++it) {
            int row = it * 4 + g;
            floatx4 v = *(floatx4*)&T2[row * 68 + cf];
            int node = base + w * 16 + row;
            ushortx4 hh;
            hh.x = f2bf(v.x); hh.y = f2bf(v.y); hh.z = f2bf(v.z); hh.w = f2bf(v.w);
            if (node < NN)
                __builtin_nontemporal_store(hh,
                    (ushortx4*)&xb[(size_t)node * C + p * 64 + cf]);
            ps[it] = v.x * ws4.x + v.y * ws4.y + v.z * ws4.z + v.w * ws4.w;
            pd[it] = v.x * wd4.x + v.y * wd4.y + v.z * wd4.z + v.w * wd4.w;
        }
        #pragma unroll
        for (int it = 0; it < 4; ++it) {
            #pragma unroll
            for (int d = 1; d < 8; d <<= 1) {
                ps[it] += __shfl_xor(ps[it], d, 64);
                pd[it] += __shfl_xor(pd[it], d, 64);
            }
        }
        if ((l & 7) == 0) {
            int hh = p * 2 + ((l & 15) >> 3);
            #pragma unroll
            for (int it = 0; it < 4; ++it) {
                int lr = w * 16 + it * 4 + g;
                s_as[lr][hh] = ps[it];
                s_ad[lr][hh] = pd[it];
            }
        }
    }

    #pragma unroll
    for (int p = 0; p < 2; ++p) {
        #pragma unroll
        for (int ntl = 0; ntl < 4; ++ntl) {
            int nt = 8 + p * 4 + ntl;
            #pragma unroll
            for (int r = 0; r < 4; ++r)
                T2[(quad * 4 + r) * 68 + ntl * 16 + lo16] = acc[nt][r];
        }
        #pragma unroll
        for (int it = 0; it < 4; ++it) {
            int row = it * 4 + g;
            floatx4 v = *(floatx4*)&T2[row * 68 + cf];
            int node = base + w * 16 + row;
            ushortx4 hh;
            hh.x = f2bf(v.x); hh.y = f2bf(v.y); hh.z = f2bf(v.z); hh.w = f2bf(v.w);
            if (node < NN)
                __builtin_nontemporal_store(hh,
                    (ushortx4*)&resb[(size_t)node * C + p * 64 + cf]);
        }
    }

    __syncthreads();
    int idx = blockIdx.x * 256 + tid;
    if (idx < NN * 4) {
        a_s[idx] = ((float*)s_as)[tid];
        a_d[idx] = ((float*)s_ad)[tid];
    }
}

// ---------------------------------------------------------------------------
// CSR build via two-level counting sort. NO global atomics anywhere.
// ---------------------------------------------------------------------------
__global__ __launch_bounds__(256)
void sort1_kernel(const int* __restrict__ dst, int* __restrict__ counts)
{
    __shared__ int h[256];
    const int tid = threadIdx.x;
    h[tid] = 0;
    __syncthreads();
    const int e0 = blockIdx.x * EPB;
    const int e1 = min(NE, e0 + EPB);
    for (int e = e0 + tid; e < e1; e += 256)
        atomicAdd(&h[dst[e] >> BSHIFT], 1);
    __syncthreads();
    counts[blockIdx.x * 256 + tid] = h[tid];
}

__global__ __launch_bounds__(256)
void sortscan_kernel(int* __restrict__ counts, int* __restrict__ bucket_base)
{
    __shared__ int wsum[4];
    const int t = threadIdx.x, lane = t & 63, wid = t >> 6;
    int run = 0;
    #pragma unroll 8
    for (int b = 0; b < NBLK1; ++b) {
        int v = counts[b * 256 + t];
        counts[b * 256 + t] = run;
        run += v;
    }
    int v0 = run, v = run;
    #pragma unroll
    for (int off = 1; off < 64; off <<= 1) {
        int u = __shfl_up(v, off, 64);
        if (lane >= off) v += u;
    }
    if (lane == 63) wsum[wid] = v;
    __syncthreads();
    if (t == 0) {
        int r = 0;
        #pragma unroll
        for (int s = 0; s < 4; ++s) { int tmp = wsum[s]; wsum[s] = r; r += tmp; }
    }
    __syncthreads();
    int excl = wsum[wid] + (v - v0);
    bucket_base[t] = excl;
    if (t == 255) bucket_base[256] = excl + v0;   // == NE
}

// pass2: scatter edges into bucket-major packed array via LDS cursors.
// bpack = (dst&511)<<20 | src   (src < 2^17)
__global__ __launch_bounds__(256)
void sort2_kernel(const int* __restrict__ src, const int* __restrict__ dst,
                  const int* __restrict__ counts,
                  const int* __restrict__ bucket_base,
                  int* __restrict__ bpack)
{
    __shared__ int cur[256];
    const int tid = threadIdx.x;
    cur[tid] = bucket_base[tid] + counts[blockIdx.x * 256 + tid];
    __syncthreads();
    const int e0 = blockIdx.x * EPB;
    const int e1 = min(NE, e0 + EPB);
    for (int e = e0 + tid; e < e1; e += 256) {
        int d = dst[e];
        int s = src[e];
        int pos = atomicAdd(&cur[d >> BSHIFT], 1);
        bpack[pos] = ((d & 511) << 20) | s;
    }
}

// pass3: per-bucket (512 nodes) CSR finalize (round-3 cheap form).
__global__ __launch_bounds__(512)
void sort3_kernel(const int* __restrict__ bpack,
                  const int* __restrict__ bucket_base,
                  int* __restrict__ row_ptr,
                  int* __restrict__ csr_src)
{
    __shared__ int cnt[512];
    __shared__ int cur[512];
    __shared__ int wsum[8];
    const int t = threadIdx.x, lane = t & 63, wid = t >> 6;
    const int b = blockIdx.x;
    const int ebeg = bucket_base[b];
    const int eend = bucket_base[b + 1];
    cnt[t] = 0;
    __syncthreads();
    for (int e = ebeg + t; e < eend; e += 512)
        atomicAdd(&cnt[bpack[e] >> 20], 1);
    __syncthreads();
    int v0 = cnt[t], v = v0;
    #pragma unroll
    for (int off = 1; off < 64; off <<= 1) {
        int u = __shfl_up(v, off, 64);
        if (lane >= off) v += u;
    }
    if (lane == 63) wsum[wid] = v;
    __syncthreads();
    if (t == 0) {
        int r = 0;
        #pragma unroll
        for (int s = 0; s < 8; ++s) { int tmp = wsum[s]; wsum[s] = r; r += tmp; }
    }
    __syncthreads();
    int excl = wsum[wid] + (v - v0);
    cur[t] = excl;
    int n = (b << BSHIFT) + t;
    if (n < NN) row_ptr[n] = ebeg + excl;
    if (b == NBUCK - 1 && t == 0) row_ptr[NN] = NE;
    __syncthreads();
    for (int e = ebeg + t; e < eend; e += 512) {
        int p = bpack[e];
        int pos = atomicAdd(&cur[p >> 20], 1);
        csr_src[ebeg + pos] = p & 0xFFFFF;
    }
}

// ---------------------------------------------------------------------------
// aggregation: QUARTER-WAVE per dst node (round-3 structure) with BATCHED
// independent gathers. Per 16-edge chunk: alpha phase writes (si, ex4) to
// padded LDS; then the chunk's si/alpha are hoisted to registers via int4/
// float4 reads and 8 xb-row gathers are issued back-to-back with NO
// inter-load dependencies -> ~8 rows in flight per quad (vs 2 before).
// LDS strides of 20 words make every access class <=2-way (free).
// Unnormalized accumulate + end reduce (round-3 denominator scheme).
// ---------------------------------------------------------------------------
__global__ __launch_bounds__(256)
void agg_kernel(const unsigned short* __restrict__ xb,
                const unsigned short* __restrict__ resb,
                const float* __restrict__ a_s,
                const float* __restrict__ a_d,
                const int* __restrict__ row_ptr,
                const int* __restrict__ csr_src,
                float* __restrict__ out)
{
    __shared__ __align__(16) int   s_srcs[4][4 * 20];      // [wave][q*20+i]
    __shared__ __align__(16) float s_alpha[4][4][4 * 20];  // [wave][q][h*20+i]
    const int tid = threadIdx.x;
    const int w   = tid >> 6;
    const int l   = tid & 63;
    const int q   = l >> 4;        // node slot within wave
    const int t16 = l & 15;        // lane within quad
    const int h   = t16 >> 2;      // head owning this lane's 8 channels

    const int n = blockIdx.x * 16 + w * 4 + q;   // < NN always (6250*16=NN)
    const int r0  = row_ptr[n];
    const int deg = row_ptr[n + 1] - r0;

    // residual row: load early (independent of gather chain)
    short8 rv = *(const short8*)&resb[(size_t)n * C + t16 * 8];
    const float4 ad4 = *(const float4*)&a_d[n * 4];

    // max degree over the 4 quads of this wave -> unified chunk loop
    int dm = deg;
    dm = max(dm, __shfl_xor(dm, 16, 64));
    dm = max(dm, __shfl_xor(dm, 32, 64));

    float acc8[8];
    #pragma unroll
    for (int j = 0; j < 8; ++j) acc8[j] = 0.f;
    float dx = 0.f, dy = 0.f, dz = 0.f, dw = 0.f;

    for (int c0 = 0; c0 < dm; c0 += 16) {
        int e = c0 + t16;
        int s = 0;
        float4 ex = {0.f, 0.f, 0.f, 0.f};
        if (e < deg) {
            s = csr_src[r0 + e];
            float4 as4 = *(const float4*)&a_s[(size_t)s * 4];
            ex.x = __expf(lrelu(as4.x + ad4.x));
            ex.y = __expf(lrelu(as4.y + ad4.y));
            ex.z = __expf(lrelu(as4.z + ad4.z));
            ex.w = __expf(lrelu(as4.w + ad4.w));
            dx += ex.x; dy += ex.y; dz += ex.z; dw += ex.w;
        }
        s_srcs[w][q * 20 + t16] = s;              // wave-private; DS in-order
        s_alpha[w][q][0 * 20 + t16] = ex.x;
        s_alpha[w][q][1 * 20 + t16] = ex.y;
        s_alpha[w][q][2 * 20 + t16] = ex.z;
        s_alpha[w][q][3 * 20 + t16] = ex.w;

        #pragma unroll
        for (int b = 0; b < 2; ++b) {
            if (c0 + b * 8 < deg) {               // quad-uniform batch gate
                int sib[8]; float alb[8];
                *(int4*)&sib[0]   = *(const int4*)&s_srcs[w][q * 20 + b * 8];
                *(int4*)&sib[4]   = *(const int4*)&s_srcs[w][q * 20 + b * 8 + 4];
                *(float4*)&alb[0] = *(const float4*)&s_alpha[w][q][h * 20 + b * 8];
                *(float4*)&alb[4] = *(const float4*)&s_alpha[w][q][h * 20 + b * 8 + 4];
                short8 uv[8];
                #pragma unroll
                for (int i = 0; i < 8; ++i)       // 8 independent gathers
                    uv[i] = *(const short8*)&xb[(size_t)sib[i] * C + t16 * 8];
                #pragma unroll
                for (int i = 0; i < 8; ++i) {
                    float al = alb[i];            // al==0 for invalid edges
                    acc8[0] = fmaf(al, bf2f((unsigned short)uv[i][0]), acc8[0]);
                    acc8[1] = fmaf(al, bf2f((unsigned short)uv[i][1]), acc8[1]);
                    acc8[2] = fmaf(al, bf2f((unsigned short)uv[i][2]), acc8[2]);
                    acc8[3] = fmaf(al, bf2f((unsigned short)uv[i][3]), acc8[3]);
                    acc8[4] = fmaf(al, bf2f((unsigned short)uv[i][4]), acc8[4]);
                    acc8[5] = fmaf(al, bf2f((unsigned short)uv[i][5]), acc8[5]);
                    acc8[6] = fmaf(al, bf2f((unsigned short)uv[i][6]), acc8[6]);
                    acc8[7] = fmaf(al, bf2f((unsigned short)uv[i][7]), acc8[7]);
                }
            }
        }
    }

    // denominator: reduce within quad (xor over lane bits 0..3)
    #pragma unroll
    for (int d = 1; d < 16; d <<= 1) {
        dx += __shfl_xor(dx, d, 64);
        dy += __shfl_xor(dy, d, 64);
        dz += __shfl_xor(dz, d, 64);
        dw += __shfl_xor(dw, d, 64);
    }
    float den = (h == 0) ? dx : (h == 1) ? dy : (h == 2) ? dz : dw;
    float inv = (deg > 0) ? 1.f / den : 0.f;

    floatx4 o0, o1;
    o0.x = bf2f((unsigned short)rv[0]) + acc8[0] * inv;
    o0.y = bf2f((unsigned short)rv[1]) + acc8[1] * inv;
    o0.z = bf2f((unsigned short)rv[2]) + acc8[2] * inv;
    o0.w = bf2f((unsigned short)rv[3]) + acc8[3] * inv;
    o1.x = bf2f((unsigned short)rv[4]) + acc8[4] * inv;
    o1.y = bf2f((unsigned short)rv[5]) + acc8[5] * inv;
    o1.z = bf2f((unsigned short)rv[6]) + acc8[6] * inv;
    o1.w = bf2f((unsigned short)rv[7]) + acc8[7] * inv;
    __builtin_nontemporal_store(o0, (floatx4*)&out[(size_t)n * C + t16 * 8]);
    __builtin_nontemporal_store(o1, (floatx4*)&out[(size_t)n * C + t16 * 8 + 4]);
}

// ---------------------------------------------------------------------------
extern "C" void kernel_launch(void* const* d_in, const int* in_sizes, int n_in,
                              void* d_out, int out_size, void* d_ws, size_t ws_size,
                              hipStream_t stream)
{
    const float* feat    = (const float*)d_in[0];
    const float* W       = (const float*)d_in[1];
    const float* att_src = (const float*)d_in[2];
    const float* att_dst = (const float*)d_in[3];
    const float* W_res   = (const float*)d_in[4];
    const int*   src     = (const int*)d_in[5];
    const int*   dst     = (const int*)d_in[6];
    float* out = (float*)d_out;

    char* p = (char*)d_ws;
    unsigned short* xb   = (unsigned short*)p; p += (size_t)NN * C * sizeof(unsigned short);
    unsigned short* resb = (unsigned short*)p; p += (size_t)NN * C * sizeof(unsigned short);
    unsigned short* Btf  = (unsigned short*)p; p += (size_t)256 * 128 * sizeof(unsigned short);
    float* a_s = (float*)p;            p += (size_t)NN * 4 * sizeof(float);
    float* a_d = (float*)p;            p += (size_t)NN * 4 * sizeof(float);
    int* row_ptr = (int*)p;            p += (size_t)(NN + 1) * sizeof(int);
    int* counts  = (int*)p;            p += (size_t)NBLK1 * 256 * sizeof(int);
    int* bucket_base = (int*)p;        p += (size_t)257 * sizeof(int);
    int* bpack   = (int*)p;            p += (size_t)NE * sizeof(int);
    int* csr_src = (int*)p;            p += (size_t)NE * sizeof(int);

    wconv_kernel<<<16, 256, 0, stream>>>(W, W_res, Btf);
    proj_kernel<<<PROJ_NB, 256, 0, stream>>>(
        feat, Btf, att_src, att_dst, xb, resb, a_s, a_d);
    sort1_kernel<<<NBLK1, 256, 0, stream>>>(dst, counts);
    sortscan_kernel<<<1, 256, 0, stream>>>(counts, bucket_base);
    sort2_kernel<<<NBLK1, 256, 0, stream>>>(src, dst, counts, bucket_base, bpack);
    sort3_kernel<<<NBUCK, 512, 0, stream>>>(bpack, bucket_base, row_ptr, csr_src);
    agg_kernel<<<NN / 16, 256, 0, stream>>>(xb, resb, a_s, a_d, row_ptr, csr_src, out);
}